// Round 5
// baseline (1068.424 us; speedup 1.0000x reference)
//
#include <hip/hip_runtime.h>
#include <hip/hip_cooperative_groups.h>

namespace cg = cooperative_groups;

#define N_SEGMENTS 50000
#define N_ROWS     1600000
#define N_FEAT     64
#define SCHUNK     1000     // scan chunk per block
#define N_CHUNKS   50       // N_SEGMENTS / SCHUNK
#define COOP_TPB   256

// Native vector type: __builtin_nontemporal_load/store require scalar/native-
// vector element pointers (HIP_vector_type<float,4> is rejected).
typedef float f32x4 __attribute__((ext_vector_type(4)));

// ---------------- Fallback 0 (round-0 verified kernel) ----------------
__global__ void seg_sum_atomic(const float* __restrict__ in,
                               const int*   __restrict__ idx,
                               float*       __restrict__ out) {
    long long t   = (long long)blockIdx.x * blockDim.x + threadIdx.x;
    long long row = t >> 6;
    int       c   = (int)(t & 63);
    if (row < (long long)N_ROWS) {
        int s = idx[row];
        float v = in[row * N_FEAT + c];
        atomicAdd(out + (long long)s * N_FEAT + c, v);
    }
}

// ================= Fallback 1: round-4 verified multi-kernel path ============
__global__ void hist_kernel(const int* __restrict__ idx, int* __restrict__ cnt) {
    int t = blockIdx.x * blockDim.x + threadIdx.x;
    int r = t << 2;
    if (r < N_ROWS) {
        int4 v = *reinterpret_cast<const int4*>(idx + r);
        atomicAdd(&cnt[v.x], 1);
        atomicAdd(&cnt[v.y], 1);
        atomicAdd(&cnt[v.z], 1);
        atomicAdd(&cnt[v.w], 1);
    }
}

__global__ void __launch_bounds__(1024) scan_part(const int* __restrict__ cnt,
                                                  int* __restrict__ base,
                                                  int* __restrict__ cursor,
                                                  int* __restrict__ csum) {
    __shared__ int part[1024];
    int b = blockIdx.x;
    int t = threadIdx.x;
    int g = b * SCHUNK + t;
    part[t] = (t < SCHUNK) ? cnt[g] : 0;
    __syncthreads();
    for (int ofs = 1; ofs < 1024; ofs <<= 1) {
        int u = (t >= ofs) ? part[t - ofs] : 0;
        __syncthreads();
        part[t] += u;
        __syncthreads();
    }
    int excl = (t == 0) ? 0 : part[t - 1];
    if (t < SCHUNK) { base[g] = excl; cursor[g] = excl; }
    if (t == 1023) csum[b] = part[1023];
}

__global__ void scan_fix(const int* __restrict__ csum,
                         int* __restrict__ off,
                         int* __restrict__ base) {
    int t = threadIdx.x;                     // 64 threads
    int orig = (t < N_CHUNKS) ? csum[t] : 0;
    int v = orig;
    for (int ofs = 1; ofs < 64; ofs <<= 1) {
        int u = __shfl_up(v, ofs);
        if (t >= ofs) v += u;
    }
    if (t < N_CHUNKS) off[t] = v - orig;
    if (t == N_CHUNKS - 1) { off[N_CHUNKS] = v; base[N_SEGMENTS] = 0; }
}

__global__ void scatter_kernel(const int* __restrict__ idx,
                               int* __restrict__ cursor,
                               const int* __restrict__ off,
                               int* __restrict__ rowids) {
    int t = blockIdx.x * blockDim.x + threadIdx.x;
    int r = t << 2;
    if (r < N_ROWS) {
        int4 v = *reinterpret_cast<const int4*>(idx + r);
        rowids[atomicAdd(&cursor[v.x], 1) + off[v.x / SCHUNK]] = r;
        rowids[atomicAdd(&cursor[v.y], 1) + off[v.y / SCHUNK]] = r + 1;
        rowids[atomicAdd(&cursor[v.z], 1) + off[v.z / SCHUNK]] = r + 2;
        rowids[atomicAdd(&cursor[v.w], 1) + off[v.w / SCHUNK]] = r + 3;
    }
}

__global__ void gather_kernel(const float* __restrict__ in,
                              const int*   __restrict__ rowids,
                              const int*   __restrict__ base,
                              const int*   __restrict__ off,
                              float*       __restrict__ out) {
    int wave = (blockIdx.x * blockDim.x + threadIdx.x) >> 6;
    int lane = threadIdx.x & 63;
    if (wave >= N_SEGMENTS) return;
    int q = lane >> 4;
    int f = lane & 15;
    int beg = base[wave]     + off[wave / SCHUNK];
    int end = base[wave + 1] + off[(wave + 1) / SCHUNK];
    f32x4 z = {0.f, 0.f, 0.f, 0.f};
    f32x4 a0 = z, a1 = z, a2 = z, a3 = z;

    for (int j0 = beg; j0 < end; j0 += 64) {
        int n = end - j0; if (n > 64) n = 64;
        int myid = (lane < n) ? rowids[j0 + lane] : 0;
#pragma unroll
        for (int k = 0; k < 64; k += 16) {
            int i0 = k + q, i1 = k + 4 + q, i2 = k + 8 + q, i3 = k + 12 + q;
            int r0 = __shfl(myid, i0 < n ? i0 : 0);
            int r1 = __shfl(myid, i1 < n ? i1 : 0);
            int r2 = __shfl(myid, i2 < n ? i2 : 0);
            int r3 = __shfl(myid, i3 < n ? i3 : 0);
            f32x4 v0 = __builtin_nontemporal_load(
                reinterpret_cast<const f32x4*>(in + (long long)r0 * N_FEAT + f * 4));
            f32x4 v1 = __builtin_nontemporal_load(
                reinterpret_cast<const f32x4*>(in + (long long)r1 * N_FEAT + f * 4));
            f32x4 v2 = __builtin_nontemporal_load(
                reinterpret_cast<const f32x4*>(in + (long long)r2 * N_FEAT + f * 4));
            f32x4 v3 = __builtin_nontemporal_load(
                reinterpret_cast<const f32x4*>(in + (long long)r3 * N_FEAT + f * 4));
            if (i0 < n) a0 += v0;
            if (i1 < n) a1 += v1;
            if (i2 < n) a2 += v2;
            if (i3 < n) a3 += v3;
        }
    }

    f32x4 a = (a0 + a1) + (a2 + a3);
    a.x += __shfl_xor(a.x, 16); a.y += __shfl_xor(a.y, 16);
    a.z += __shfl_xor(a.z, 16); a.w += __shfl_xor(a.w, 16);
    a.x += __shfl_xor(a.x, 32); a.y += __shfl_xor(a.y, 32);
    a.z += __shfl_xor(a.z, 32); a.w += __shfl_xor(a.w, 32);

    if (q == 0) {
        __builtin_nontemporal_store(a,
            reinterpret_cast<f32x4*>(out + (size_t)wave * N_FEAT + f * 4));
    }
}

// ================= Primary: single cooperative fused pipeline ================
// Phases separated by grid.sync(); all phases grid-stride so any block count
// works. One dispatch -> visible in rocprof top-5 with counters.
__global__ void __launch_bounds__(COOP_TPB) fused_pipeline(
        const float* __restrict__ in,
        const int*   __restrict__ idx,
        int* __restrict__ cnt,
        int* __restrict__ base,
        int* __restrict__ cursor,
        int* __restrict__ csum,
        int* __restrict__ off,
        int* __restrict__ rowids,
        float* __restrict__ out)
{
    cg::grid_group grid = cg::this_grid();
    __shared__ int part[COOP_TPB];

    const int tid      = threadIdx.x;
    const int gtid     = blockIdx.x * COOP_TPB + tid;
    const int nthreads = gridDim.x * COOP_TPB;

    // ---- P0: zero counters (replaces the memset dispatch) ----
    for (int i = gtid; i < N_SEGMENTS; i += nthreads) cnt[i] = 0;
    grid.sync();

    // ---- P1: histogram (int4, 4 rows/thread) ----
    for (int u = gtid; u < N_ROWS / 4; u += nthreads) {
        int4 v = *reinterpret_cast<const int4*>(idx + (u << 2));
        atomicAdd(&cnt[v.x], 1);
        atomicAdd(&cnt[v.y], 1);
        atomicAdd(&cnt[v.z], 1);
        atomicAdd(&cnt[v.w], 1);
    }
    grid.sync();

    // ---- P2: per-chunk exclusive scan, blocks 0..49, 4 elems/thread ----
    if (blockIdx.x < N_CHUNKS) {
        const int b = blockIdx.x;
        int e0 = 0, e1 = 0, e2 = 0, e3 = 0, s = 0;
        if (tid < 250) {                         // 250*4 = 1000 = SCHUNK
            const int g = b * SCHUNK + (tid << 2);
            e0 = cnt[g]; e1 = cnt[g + 1]; e2 = cnt[g + 2]; e3 = cnt[g + 3];
            s = e0 + e1 + e2 + e3;
        }
        part[tid] = s;
        __syncthreads();
        for (int ofs = 1; ofs < COOP_TPB; ofs <<= 1) {
            int u = (tid >= ofs) ? part[tid - ofs] : 0;
            __syncthreads();
            part[tid] += u;
            __syncthreads();
        }
        if (tid < 250) {
            int run = (tid == 0) ? 0 : part[tid - 1];
            const int g = b * SCHUNK + (tid << 2);
            base[g]     = run; cursor[g]     = run; run += e0;
            base[g + 1] = run; cursor[g + 1] = run; run += e1;
            base[g + 2] = run; cursor[g + 2] = run; run += e2;
            base[g + 3] = run; cursor[g + 3] = run;
        }
        if (tid == COOP_TPB - 1) csum[b] = part[COOP_TPB - 1];
    }
    grid.sync();

    // ---- P2b: scan the 50 chunk totals (block 0, first wave) ----
    if (blockIdx.x == 0 && tid < 64) {
        int orig = (tid < N_CHUNKS) ? csum[tid] : 0;
        int v = orig;
        for (int ofs = 1; ofs < 64; ofs <<= 1) {
            int u = __shfl_up(v, ofs);
            if (tid >= ofs) v += u;
        }
        if (tid < N_CHUNKS) off[tid] = v - orig;
        if (tid == N_CHUNKS - 1) { off[N_CHUNKS] = v; base[N_SEGMENTS] = 0; }
    }
    grid.sync();

    // ---- P3: scatter row ids (nontemporal stores) ----
    for (int u = gtid; u < N_ROWS / 4; u += nthreads) {
        const int r = u << 2;
        int4 v = *reinterpret_cast<const int4*>(idx + r);
        int p0 = atomicAdd(&cursor[v.x], 1) + off[v.x / SCHUNK];
        int p1 = atomicAdd(&cursor[v.y], 1) + off[v.y / SCHUNK];
        int p2 = atomicAdd(&cursor[v.z], 1) + off[v.z / SCHUNK];
        int p3 = atomicAdd(&cursor[v.w], 1) + off[v.w / SCHUNK];
        __builtin_nontemporal_store(r,     rowids + p0);
        __builtin_nontemporal_store(r + 1, rowids + p1);
        __builtin_nontemporal_store(r + 2, rowids + p2);
        __builtin_nontemporal_store(r + 3, rowids + p3);
    }
    grid.sync();

    // ---- P4: gather, one wave per segment, grid-stride over segments ----
    // Wave-uniform `k < n` guards skip the clamped duplicate loads (~40%).
    // rowids is padded by 64 ints so the prefetch load needs no guard.
    const int lane = tid & 63;
    const int q = lane >> 4;
    const int f = lane & 15;
    const int wstride = nthreads >> 6;
    for (int w = (gtid >> 6); w < N_SEGMENTS; w += wstride) {
        int beg = base[w]     + off[w / SCHUNK];
        int end = base[w + 1] + off[(w + 1) / SCHUNK];
        f32x4 z = {0.f, 0.f, 0.f, 0.f};
        f32x4 a0 = z, a1 = z, a2 = z, a3 = z;

        for (int j0 = beg; j0 < end; j0 += 64) {
            int n = end - j0; if (n > 64) n = 64;
            int myid = rowids[j0 + lane];        // padded: safe unguarded
#pragma unroll
            for (int k = 0; k < 64; k += 16) {
                if (k < n) {                     // wave-uniform: skip dupes
                    int i0 = k + q, i1 = k + 4 + q, i2 = k + 8 + q, i3 = k + 12 + q;
                    int r0 = __shfl(myid, i0 < n ? i0 : 0);
                    int r1 = __shfl(myid, i1 < n ? i1 : 0);
                    int r2 = __shfl(myid, i2 < n ? i2 : 0);
                    int r3 = __shfl(myid, i3 < n ? i3 : 0);
                    f32x4 v0 = __builtin_nontemporal_load(
                        reinterpret_cast<const f32x4*>(in + (long long)r0 * N_FEAT + f * 4));
                    f32x4 v1 = __builtin_nontemporal_load(
                        reinterpret_cast<const f32x4*>(in + (long long)r1 * N_FEAT + f * 4));
                    f32x4 v2 = __builtin_nontemporal_load(
                        reinterpret_cast<const f32x4*>(in + (long long)r2 * N_FEAT + f * 4));
                    f32x4 v3 = __builtin_nontemporal_load(
                        reinterpret_cast<const f32x4*>(in + (long long)r3 * N_FEAT + f * 4));
                    if (i0 < n) a0 += v0;
                    if (i1 < n) a1 += v1;
                    if (i2 < n) a2 += v2;
                    if (i3 < n) a3 += v3;
                }
            }
        }

        f32x4 a = (a0 + a1) + (a2 + a3);
        a.x += __shfl_xor(a.x, 16); a.y += __shfl_xor(a.y, 16);
        a.z += __shfl_xor(a.z, 16); a.w += __shfl_xor(a.w, 16);
        a.x += __shfl_xor(a.x, 32); a.y += __shfl_xor(a.y, 32);
        a.z += __shfl_xor(a.z, 32); a.w += __shfl_xor(a.w, 32);

        if (q == 0) {
            __builtin_nontemporal_store(a,
                reinterpret_cast<f32x4*>(out + (size_t)w * N_FEAT + f * 4));
        }
    }
}

extern "C" void kernel_launch(void* const* d_in, const int* in_sizes, int n_in,
                              void* d_out, int out_size, void* d_ws, size_t ws_size,
                              hipStream_t stream) {
    const float* in  = (const float*)d_in[0];
    const int*   idx = (const int*)d_in[1];
    float*       out = (float*)d_out;

    // ws ints: cnt[50000] | base[50001] | cursor[50000] | csum[64] | off[64]
    //        | rowids[1.6M + 64 pad]
    const size_t need = ((size_t)N_SEGMENTS * 3 + 1 + 128 + N_ROWS + 64) * sizeof(int);
    if (ws_size < need) {
        (void)hipMemsetAsync(d_out, 0, (size_t)out_size * sizeof(float), stream);
        const long long total = (long long)N_ROWS * N_FEAT;
        const int block = 256;
        const long long grid = (total + block - 1) / block;
        seg_sum_atomic<<<(unsigned)grid, block, 0, stream>>>(in, idx, out);
        return;
    }

    int* cnt    = (int*)d_ws;
    int* base   = cnt + N_SEGMENTS;          // [N_SEGMENTS+1]
    int* cursor = base + N_SEGMENTS + 1;
    int* csum   = cursor + N_SEGMENTS;       // [64]
    int* off    = csum + 64;                 // [64] (uses N_CHUNKS+1)
    int* rowids = off + 64;                  // [N_ROWS + 64]

    // --- Primary: cooperative fused pipeline ---
    static int coop_blocks = 0;
    if (coop_blocks == 0) {
        int maxb = 0;
        if (hipOccupancyMaxActiveBlocksPerMultiprocessor(
                &maxb, fused_pipeline, COOP_TPB, 0) != hipSuccess || maxb <= 0)
            maxb = 4;                        // conservative
        coop_blocks = maxb * 256;            // 256 CUs on MI355X
        if (coop_blocks > 2048) coop_blocks = 2048;
    }

    void* args[] = { (void*)&in, (void*)&idx, (void*)&cnt, (void*)&base,
                     (void*)&cursor, (void*)&csum, (void*)&off,
                     (void*)&rowids, (void*)&out };
    hipError_t err = hipLaunchCooperativeKernel((const void*)fused_pipeline,
                                                dim3(coop_blocks), dim3(COOP_TPB),
                                                args, 0, stream);
    if (err == hipSuccess) return;

    // --- Fallback: round-4 verified multi-kernel path ---
    (void)hipMemsetAsync(cnt, 0, (size_t)N_SEGMENTS * sizeof(int), stream);
    const int block = 256;
    const int gridRows = (N_ROWS / 4 + block - 1) / block;
    hist_kernel   <<<gridRows, block, 0, stream>>>(idx, cnt);
    scan_part     <<<N_CHUNKS, 1024, 0, stream>>>(cnt, base, cursor, csum);
    scan_fix      <<<1, 64, 0, stream>>>(csum, off, base);
    scatter_kernel<<<gridRows, block, 0, stream>>>(idx, cursor, off, rowids);
    const int gridGather = (N_SEGMENTS * 64) / 256;
    gather_kernel <<<gridGather, block, 0, stream>>>(in, rowids, base, off, out);
}